// Round 5
// baseline (280.325 us; speedup 1.0000x reference)
//
#include <hip/hip_runtime.h>
#include <hip/hip_bf16.h>
#include <math.h>

typedef __bf16 bf16_t;
typedef bf16_t bf16x8 __attribute__((ext_vector_type(8)));
typedef float f32x4 __attribute__((ext_vector_type(4)));

#define T_TOK 8192
#define HDIM  1024
#define IDIM  512
#define NEXP  8
#define NTOT  12
#define MAXROWS (2 * T_TOK + NEXP * 128)   // 17408
#define MAX_MTILES (MAXROWS / 128)         // 136
#define BM 128
#define BN 64
#define BK 32

// ---------------- router: 4 tokens/block, one wave per token ----------------
__global__ void router_kernel(const float* __restrict__ x, const float* __restrict__ rw,
                              const float* __restrict__ bias,
                              int* __restrict__ tk_e, float* __restrict__ tk_w,
                              float* __restrict__ zscale) {
  int t = blockIdx.x * 4 + (threadIdx.x >> 6);
  int l = threadIdx.x & 63;
  const float4* xr = (const float4*)(x + (size_t)t * HDIM);
  float4 xv[4];
#pragma unroll
  for (int i = 0; i < 4; i++) xv[i] = xr[l + 64 * i];
  float part[NTOT];
#pragma unroll
  for (int e = 0; e < NTOT; e++) {
    const float4* wr = (const float4*)(rw + (size_t)e * HDIM);
    float s = 0.f;
#pragma unroll
    for (int i = 0; i < 4; i++) {
      float4 w = wr[l + 64 * i];
      s += xv[i].x * w.x + xv[i].y * w.y + xv[i].z * w.z + xv[i].w * w.w;
    }
    part[e] = s;
  }
#pragma unroll
  for (int off = 32; off > 0; off >>= 1)
#pragma unroll
    for (int e = 0; e < NTOT; e++) part[e] += __shfl_down(part[e], off);

  if (l == 0) {
    float mx = part[0];
#pragma unroll
    for (int e = 1; e < NTOT; e++) mx = fmaxf(mx, part[e]);
    float p[NTOT], den = 0.f;
#pragma unroll
    for (int e = 0; e < NTOT; e++) { p[e] = expf(part[e] - mx); den += p[e]; }
    float inv = 1.f / den;
#pragma unroll
    for (int e = 0; e < NTOT; e++) p[e] *= inv;
    float s0 = -1e30f, s1 = -1e30f; int i0 = 0, i1 = 0;
#pragma unroll
    for (int e = 0; e < NTOT; e++) {
      float v = p[e] + bias[e];
      if (v > s0) { s1 = s0; i1 = i0; s0 = v; i0 = e; }
      else if (v > s1) { s1 = v; i1 = e; }
    }
    float zs = 0.f;
    int idx[2] = { i0, i1 };
#pragma unroll
    for (int k = 0; k < 2; k++) {
      int e = idx[k];
      float w = p[e];
      if (e >= NEXP) { zs += w; tk_e[2 * t + k] = -1; tk_w[2 * t + k] = 0.f; }
      else           { tk_e[2 * t + k] = e; tk_w[2 * t + k] = w; }
    }
    zscale[t] = zs;
  }
}

// ---------------- zero counts ----------------
__global__ void zero_counts_kernel(int* __restrict__ counts) {
  if (threadIdx.x < NEXP) counts[threadIdx.x] = 0;
}

// ---------------- count ----------------
__global__ void count_kernel(const int* __restrict__ tk_e, int* __restrict__ counts) {
  __shared__ int lc[NEXP];
  int tid = threadIdx.x;
  if (tid < NEXP) lc[tid] = 0;
  __syncthreads();
  int t = blockIdx.x * blockDim.x + tid;
  int e0 = tk_e[2 * t], e1 = tk_e[2 * t + 1];
  if (e0 >= 0) atomicAdd(&lc[e0], 1);
  if (e1 >= 0) atomicAdd(&lc[e1], 1);
  __syncthreads();
  if (tid < NEXP) atomicAdd(&counts[tid], lc[tid]);
}

// ---------------- scan: offsets + tile list + zero pad sel entries ----------------
__global__ void scan_kernel(const int* __restrict__ counts, int* __restrict__ off_pad,
                            int* __restrict__ cursor, int* __restrict__ total_rows,
                            int* __restrict__ tile_e, int* __restrict__ tile_p0,
                            int* __restrict__ n_mtiles,
                            int* __restrict__ sel_tok, float* __restrict__ sel_w) {
  __shared__ int s_off[NEXP], s_cnt[NEXP];
  if (threadIdx.x == 0) {
    int run = 0, nt = 0;
    for (int e = 0; e < NEXP; e++) {
      s_off[e] = run; s_cnt[e] = counts[e];
      off_pad[e] = run;
      cursor[e] = run;
      int ntile = (s_cnt[e] + 127) / 128;
      for (int i = 0; i < ntile; i++) {
        tile_e[nt] = e;
        tile_p0[nt] = run + i * 128;
        nt++;
      }
      run += ntile * 128;
    }
    *total_rows = run;
    *n_mtiles = nt;
  }
  __syncthreads();
  for (int i = threadIdx.x; i < NEXP * 128; i += blockDim.x) {
    int e = i >> 7, idx = i & 127;
    int c = s_cnt[e];
    int padded = ((c + 127) / 128) * 128;
    int pos = c + idx;
    if (pos < padded) { sel_tok[s_off[e] + pos] = 0; sel_w[s_off[e] + pos] = 0.f; }
  }
}

// ---------------- assign ----------------
__global__ void assign_kernel(const int* __restrict__ tk_e, const float* __restrict__ tk_w,
                              int* __restrict__ cursor, int* __restrict__ sel_tok,
                              float* __restrict__ sel_w, int* __restrict__ pos) {
  __shared__ int lc[NEXP];
  __shared__ int lbase[NEXP];
  int tid = threadIdx.x;
  if (tid < NEXP) lc[tid] = 0;
  __syncthreads();
  int t = blockIdx.x * blockDim.x + tid;
  int e0 = tk_e[2 * t], e1 = tk_e[2 * t + 1];
  int r0 = (e0 >= 0) ? atomicAdd(&lc[e0], 1) : -1;
  int r1 = (e1 >= 0) ? atomicAdd(&lc[e1], 1) : -1;
  __syncthreads();
  if (tid < NEXP) lbase[tid] = atomicAdd(&cursor[tid], lc[tid]);
  __syncthreads();
  int p0 = -1, p1 = -1;
  if (e0 >= 0) { p0 = lbase[e0] + r0; sel_tok[p0] = t; sel_w[p0] = 2.5f * tk_w[2 * t]; }
  if (e1 >= 0) { p1 = lbase[e1] + r1; sel_tok[p1] = t; sel_w[p1] = 2.5f * tk_w[2 * t + 1]; }
  pos[2 * t] = p0;
  pos[2 * t + 1] = p1;
}

// ---------------- gather+cast: xg[p,:] = bf16(x[sel_tok[p],:]) ----------------
__global__ void gather_cast_kernel(const float* __restrict__ x, const int* __restrict__ sel_tok,
                                   const int* __restrict__ total_rows, bf16_t* __restrict__ xg) {
  size_t gid = (size_t)blockIdx.x * blockDim.x + threadIdx.x;
  size_t p = gid >> 7;
  if (p >= (size_t)*total_rows) return;
  size_t j = (gid & 127) << 3;
  int t = sel_tok[p];
  float4 a = *(const float4*)&x[(size_t)t * HDIM + j];
  float4 b = *(const float4*)&x[(size_t)t * HDIM + j + 4];
  bf16x8 o;
  o[0] = (bf16_t)a.x; o[1] = (bf16_t)a.y; o[2] = (bf16_t)a.z; o[3] = (bf16_t)a.w;
  o[4] = (bf16_t)b.x; o[5] = (bf16_t)b.y; o[6] = (bf16_t)b.z; o[7] = (bf16_t)b.w;
  *(bf16x8*)&xg[p * HDIM + j] = o;
}

__device__ __forceinline__ bf16x8 cvt8(float4 f0, float4 f1) {
  bf16x8 t;
  t[0] = (bf16_t)f0.x; t[1] = (bf16_t)f0.y; t[2] = (bf16_t)f0.z; t[3] = (bf16_t)f0.w;
  t[4] = (bf16_t)f1.x; t[5] = (bf16_t)f1.y; t[6] = (bf16_t)f1.z; t[7] = (bf16_t)f1.w;
  return t;
}

// ---------------- fused GEMM1+SiLU: 128x64 tile (32 gate + 32 up cols) ----------------
// LDS col-swizzle: element (row, chunk j) stored at chunk j ^ ((row>>1)&3).
__global__ __launch_bounds__(256) void gemm1_kernel(
    const bf16_t* __restrict__ xg, const float* __restrict__ w13,
    const int* __restrict__ tile_e, const int* __restrict__ tile_p0,
    const int* __restrict__ n_mtiles, bf16_t* __restrict__ actb) {
  const int ti = blockIdx.x;
  if (ti >= *n_mtiles) return;
  const int e = tile_e[ti];
  const int p0 = tile_p0[ti];
  const int g0 = blockIdx.y * 32;

  __shared__ alignas(16) bf16_t As[2][BM * BK];
  __shared__ alignas(16) bf16_t Bs[2][BN * BK];

  const int tid = threadIdx.x;
  const int w = tid >> 6, l = tid & 63;
  const int quad = l >> 4, c16 = l & 15;

  // A staging: row ar (0..127), chunks ac2, ac2+1 (8 bf16 each)
  const int ar = tid >> 1;
  const int ac2 = (tid & 1) * 2;
  const int swzA = (ar >> 1) & 3;
  const bf16_t* Ap = xg + (size_t)(p0 + ar) * HDIM + ac2 * 8;
  const int aw0 = ar * BK + ((ac2 ^ swzA) * 8);
  const int aw1 = ar * BK + (((ac2 + 1) ^ swzA) * 8);

  // B staging: row br (0..63) -> w13 col (gate for br<32, up for br>=32), chunk bc
  const int br = tid >> 2;
  const int bc = tid & 3;
  const int wcol = g0 + (br & 31) + ((br >> 5) ? IDIM : 0);
  const float* Bp = w13 + (size_t)e * (2 * IDIM) * HDIM + (size_t)wcol * HDIM + bc * 8;
  const int bw0 = br * BK + ((bc ^ ((br >> 1) & 3)) * 8);

  f32x4 acc[2][4];
#pragma unroll
  for (int i = 0; i < 2; i++)
#pragma unroll
    for (int j = 0; j < 4; j++) acc[i][j] = (f32x4){0.f, 0.f, 0.f, 0.f};

  // frag read offsets (swizzled)
  int aoff[2], boff[4];
#pragma unroll
  for (int mt = 0; mt < 2; mt++) {
    int r = w * 32 + mt * 16 + c16;
    aoff[mt] = r * BK + ((quad ^ ((r >> 1) & 3)) * 8);
  }
#pragma unroll
  for (int nt = 0; nt < 4; nt++) {
    int r = nt * 16 + c16;
    boff[nt] = r * BK + ((quad ^ ((r >> 1) & 3)) * 8);
  }

  int4 a0, a1; float4 b0, b1;
  // preload tile 0
  a0 = *(const int4*)(Ap);
  a1 = *(const int4*)(Ap + 8);
  b0 = *(const float4*)(Bp);
  b1 = *(const float4*)(Bp + 4);
  *(int4*)&As[0][aw0] = a0;
  *(int4*)&As[0][aw1] = a1;
  *(bf16x8*)&Bs[0][bw0] = cvt8(b0, b1);
  __syncthreads();

  int p = 0;
  for (int t = 1; t < HDIM / BK; ++t) {
    const int k0 = t * BK;
    // prefetch next tile into registers
    a0 = *(const int4*)(Ap + k0);
    a1 = *(const int4*)(Ap + k0 + 8);
    b0 = *(const float4*)(Bp + k0);
    b1 = *(const float4*)(Bp + k0 + 4);
    // compute current tile
    {
      const bf16_t* Asp = As[p];
      const bf16_t* Bsp = Bs[p];
      bf16x8 af[2], bfv[4];
#pragma unroll
      for (int mt = 0; mt < 2; mt++) af[mt] = *(const bf16x8*)&Asp[aoff[mt]];
#pragma unroll
      for (int nt = 0; nt < 4; nt++) bfv[nt] = *(const bf16x8*)&Bsp[boff[nt]];
#pragma unroll
      for (int mt = 0; mt < 2; mt++)
#pragma unroll
        for (int nt = 0; nt < 4; nt++)
          acc[mt][nt] = __builtin_amdgcn_mfma_f32_16x16x32_bf16(af[mt], bfv[nt], acc[mt][nt], 0, 0, 0);
    }
    // stage next tile
    *(int4*)&As[p ^ 1][aw0] = a0;
    *(int4*)&As[p ^ 1][aw1] = a1;
    *(bf16x8*)&Bs[p ^ 1][bw0] = cvt8(b0, b1);
    __syncthreads();
    p ^= 1;
  }
  {
    const bf16_t* Asp = As[p];
    const bf16_t* Bsp = Bs[p];
    bf16x8 af[2], bfv[4];
#pragma unroll
    for (int mt = 0; mt < 2; mt++) af[mt] = *(const bf16x8*)&Asp[aoff[mt]];
#pragma unroll
    for (int nt = 0; nt < 4; nt++) bfv[nt] = *(const bf16x8*)&Bsp[boff[nt]];
#pragma unroll
    for (int mt = 0; mt < 2; mt++)
#pragma unroll
      for (int nt = 0; nt < 4; nt++)
        acc[mt][nt] = __builtin_amdgcn_mfma_f32_16x16x32_bf16(af[mt], bfv[nt], acc[mt][nt], 0, 0, 0);
  }

  // epilogue: act = silu(gate)*up; gate = acc[mt][nt], up = acc[mt][nt+2]
#pragma unroll
  for (int mt = 0; mt < 2; mt++) {
    int rowb = p0 + w * 32 + mt * 16 + quad * 4;
#pragma unroll
    for (int nt = 0; nt < 2; nt++) {
      int col = g0 + nt * 16 + c16;
#pragma unroll
      for (int r = 0; r < 4; r++) {
        float g = acc[mt][nt][r];
        float u = acc[mt][nt + 2][r];
        actb[(size_t)(rowb + r) * IDIM + col] = (bf16_t)(g / (1.f + expf(-g)) * u);
      }
    }
  }
}

// ---------------- GEMM2: 128x64 tile, eo = sel_w * (act @ w2^T) ----------------
__global__ __launch_bounds__(256) void gemm2_kernel(
    const bf16_t* __restrict__ actb, const float* __restrict__ w2,
    const float* __restrict__ sel_w, const int* __restrict__ tile_e,
    const int* __restrict__ tile_p0, const int* __restrict__ n_mtiles,
    bf16_t* __restrict__ eob) {
  const int ti = blockIdx.x;
  if (ti >= *n_mtiles) return;
  const int e = tile_e[ti];
  const int p0 = tile_p0[ti];
  const int n0 = blockIdx.y * BN;

  __shared__ alignas(16) bf16_t As[2][BM * BK];
  __shared__ alignas(16) bf16_t Bs[2][BN * BK];

  const int tid = threadIdx.x;
  const int w = tid >> 6, l = tid & 63;
  const int quad = l >> 4, c16 = l & 15;

  const int ar = tid >> 1;
  const int ac2 = (tid & 1) * 2;
  const int swzA = (ar >> 1) & 3;
  const bf16_t* Ap = actb + (size_t)(p0 + ar) * IDIM + ac2 * 8;
  const int aw0 = ar * BK + ((ac2 ^ swzA) * 8);
  const int aw1 = ar * BK + (((ac2 + 1) ^ swzA) * 8);

  const int br = tid >> 2;
  const int bc = tid & 3;
  const float* Bp = w2 + (size_t)e * HDIM * IDIM + (size_t)(n0 + br) * IDIM + bc * 8;
  const int bw0 = br * BK + ((bc ^ ((br >> 1) & 3)) * 8);

  f32x4 acc[2][4];
#pragma unroll
  for (int i = 0; i < 2; i++)
#pragma unroll
    for (int j = 0; j < 4; j++) acc[i][j] = (f32x4){0.f, 0.f, 0.f, 0.f};

  int aoff[2], boff[4];
#pragma unroll
  for (int mt = 0; mt < 2; mt++) {
    int r = w * 32 + mt * 16 + c16;
    aoff[mt] = r * BK + ((quad ^ ((r >> 1) & 3)) * 8);
  }
#pragma unroll
  for (int nt = 0; nt < 4; nt++) {
    int r = nt * 16 + c16;
    boff[nt] = r * BK + ((quad ^ ((r >> 1) & 3)) * 8);
  }

  int4 a0, a1; float4 b0, b1;
  a0 = *(const int4*)(Ap);
  a1 = *(const int4*)(Ap + 8);
  b0 = *(const float4*)(Bp);
  b1 = *(const float4*)(Bp + 4);
  *(int4*)&As[0][aw0] = a0;
  *(int4*)&As[0][aw1] = a1;
  *(bf16x8*)&Bs[0][bw0] = cvt8(b0, b1);
  __syncthreads();

  int p = 0;
  for (int t = 1; t < IDIM / BK; ++t) {
    const int k0 = t * BK;
    a0 = *(const int4*)(Ap + k0);
    a1 = *(const int4*)(Ap + k0 + 8);
    b0 = *(const float4*)(Bp + k0);
    b1 = *(const float4*)(Bp + k0 + 4);
    {
      const bf16_t* Asp = As[p];
      const bf16_t* Bsp = Bs[p];
      bf16x8 af[2], bfv[4];
#pragma unroll
      for (int mt = 0; mt < 2; mt++) af[mt] = *(const bf16x8*)&Asp[aoff[mt]];
#pragma unroll
      for (int nt = 0; nt < 4; nt++) bfv[nt] = *(const bf16x8*)&Bsp[boff[nt]];
#pragma unroll
      for (int mt = 0; mt < 2; mt++)
#pragma unroll
        for (int nt = 0; nt < 4; nt++)
          acc[mt][nt] = __builtin_amdgcn_mfma_f32_16x16x32_bf16(af[mt], bfv[nt], acc[mt][nt], 0, 0, 0);
    }
    *(int4*)&As[p ^ 1][aw0] = a0;
    *(int4*)&As[p ^ 1][aw1] = a1;
    *(bf16x8*)&Bs[p ^ 1][bw0] = cvt8(b0, b1);
    __syncthreads();
    p ^= 1;
  }
  {
    const bf16_t* Asp = As[p];
    const bf16_t* Bsp = Bs[p];
    bf16x8 af[2], bfv[4];
#pragma unroll
    for (int mt = 0; mt < 2; mt++) af[mt] = *(const bf16x8*)&Asp[aoff[mt]];
#pragma unroll
    for (int nt = 0; nt < 4; nt++) bfv[nt] = *(const bf16x8*)&Bsp[boff[nt]];
#pragma unroll
    for (int mt = 0; mt < 2; mt++)
#pragma unroll
      for (int nt = 0; nt < 4; nt++)
        acc[mt][nt] = __builtin_amdgcn_mfma_f32_16x16x32_bf16(af[mt], bfv[nt], acc[mt][nt], 0, 0, 0);
  }

#pragma unroll
  for (int mt = 0; mt < 2; mt++) {
    int rowb = w * 32 + mt * 16 + quad * 4;
    float cw[4];
#pragma unroll
    for (int r = 0; r < 4; r++) cw[r] = sel_w[p0 + rowb + r];
#pragma unroll
    for (int nt = 0; nt < 4; nt++) {
      int col = n0 + nt * 16 + c16;
#pragma unroll
      for (int r = 0; r < 4; r++)
        eob[(size_t)(p0 + rowb + r) * HDIM + col] = (bf16_t)(cw[r] * acc[mt][nt][r]);
    }
  }
}

// ---------------- final combine ----------------
__global__ void combine_kernel(const float* __restrict__ x, const float* __restrict__ zscale,
                               const int* __restrict__ pos, const bf16_t* __restrict__ eob,
                               float* __restrict__ out) {
  size_t gid = (size_t)blockIdx.x * blockDim.x + threadIdx.x;
  size_t t = gid >> 7;
  size_t j = (gid & 127) << 3;
  float zs = zscale[t];
  int p0 = pos[2 * t], p1 = pos[2 * t + 1];
  float4 a = *(const float4*)&x[t * HDIM + j];
  float4 b = *(const float4*)&x[t * HDIM + j + 4];
  float o[8] = { zs * a.x, zs * a.y, zs * a.z, zs * a.w,
                 zs * b.x, zs * b.y, zs * b.z, zs * b.w };
  if (p0 >= 0) {
    bf16x8 v = *(const bf16x8*)&eob[(size_t)p0 * HDIM + j];
#pragma unroll
    for (int k = 0; k < 8; k++) o[k] += (float)v[k];
  }
  if (p1 >= 0) {
    bf16x8 v = *(const bf16x8*)&eob[(size_t)p1 * HDIM + j];
#pragma unroll
    for (int k = 0; k < 8; k++) o[k] += (float)v[k];
  }
  *(float4*)&out[t * HDIM + j] = make_float4(o[0], o[1], o[2], o[3]);
  *(float4*)&out[t * HDIM + j + 4] = make_float4(o[4], o[5], o[6], o[7]);
}

extern "C" void kernel_launch(void* const* d_in, const int* in_sizes, int n_in,
                              void* d_out, int out_size, void* d_ws, size_t ws_size,
                              hipStream_t stream) {
  const float* x    = (const float*)d_in[0];
  const float* rw   = (const float*)d_in[1];
  const float* bias = (const float*)d_in[2];
  const float* w13  = (const float*)d_in[3];
  const float* w2   = (const float*)d_in[4];
  float* out = (float*)d_out;

  char* ws = (char*)d_ws;
  bf16_t* xg   = (bf16_t*)ws;  ws += (size_t)MAXROWS * HDIM * 2;
  bf16_t* actb = (bf16_t*)ws;  ws += (size_t)MAXROWS * IDIM * 2;
  bf16_t* eob  = (bf16_t*)ws;  ws += (size_t)MAXROWS * HDIM * 2;
  int*   tk_e    = (int*)ws;   ws += (size_t)T_TOK * 2 * 4;
  float* tk_w    = (float*)ws; ws += (size_t)T_TOK * 2 * 4;
  float* zscale  = (float*)ws; ws += (size_t)T_TOK * 4;
  int*   pos     = (int*)ws;   ws += (size_t)T_TOK * 2 * 4;
  int*   sel_tok = (int*)ws;   ws += (size_t)MAXROWS * 4;
  float* sel_w   = (float*)ws; ws += (size_t)MAXROWS * 4;
  int*   counts  = (int*)ws;   ws += NEXP * 4;
  int*   off_pad = (int*)ws;   ws += NEXP * 4;
  int*   cursor  = (int*)ws;   ws += NEXP * 4;
  int*   total_rows = (int*)ws; ws += 4;
  int*   tile_e  = (int*)ws;   ws += MAX_MTILES * 4;
  int*   tile_p0 = (int*)ws;   ws += MAX_MTILES * 4;
  int*   n_mtiles = (int*)ws;  ws += 4;

  // routing pipeline
  zero_counts_kernel<<<1, 64, 0, stream>>>(counts);
  router_kernel<<<T_TOK / 4, 256, 0, stream>>>(x, rw, bias, tk_e, tk_w, zscale);
  count_kernel<<<T_TOK / 256, 256, 0, stream>>>(tk_e, counts);
  scan_kernel<<<1, 256, 0, stream>>>(counts, off_pad, cursor, total_rows,
                                     tile_e, tile_p0, n_mtiles, sel_tok, sel_w);
  assign_kernel<<<T_TOK / 256, 256, 0, stream>>>(tk_e, tk_w, cursor, sel_tok, sel_w, pos);
  gather_cast_kernel<<<(size_t)MAXROWS * (HDIM / 8) / 256, 256, 0, stream>>>(
      x, sel_tok, total_rows, xg);

  // pipelined grouped GEMMs (fp32 weights consumed directly)
  gemm1_kernel<<<dim3(MAX_MTILES, IDIM / 32), 256, 0, stream>>>(
      xg, w13, tile_e, tile_p0, n_mtiles, actb);
  gemm2_kernel<<<dim3(MAX_MTILES, HDIM / BN), 256, 0, stream>>>(
      actb, w2, sel_w, tile_e, tile_p0, n_mtiles, eob);

  // out = zscale*x + routed contributions
  combine_kernel<<<(size_t)T_TOK * HDIM / 8 / 256, 256, 0, stream>>>(
      x, zscale, pos, eob, out);
}